// Round 27
// baseline (517.256 us; speedup 1.0000x reference)
//
#include <hip/hip_runtime.h>
#include <cstddef>
#include <cstdint>

#define T_ 2048
#define H_ 1024
#define NH_ 16
#define LCTX 512
#define NC 64     // number of chunks
#define CL 32     // chunk length (NC*CL == T_)

typedef __attribute__((ext_vector_type(4))) float f4;
typedef __attribute__((ext_vector_type(4))) unsigned short u16x4;
typedef __attribute__((ext_vector_type(8))) short bf16x8;
typedef __attribute__((ext_vector_type(4))) float f32x4;

#define REP8(X) X(0) X(1) X(2) X(3) X(4) X(5) X(6) X(7)

__device__ __forceinline__ float sgm(float x) { return 1.0f / (1.0f + expf(-x)); }
__device__ __forceinline__ f4 f4splat(float v) { f4 r; r.x = v; r.y = v; r.z = v; r.w = v; return r; }
__device__ __forceinline__ float hsum4(f4 v) { return (v.x + v.y) + (v.z + v.w); }

__device__ __forceinline__ float rdlane(float v, int l) {
    return __uint_as_float(__builtin_amdgcn_readlane(__float_as_uint(v), l));
}

__device__ __forceinline__ unsigned short f2bf(float x) {   // RNE (weights, one-time)
    unsigned u = __float_as_uint(x);
    u += 0x7FFFu + ((u >> 16) & 1u);
    return (unsigned short)(u >> 16);
}
__device__ __forceinline__ float bf2f(unsigned short h) {
    return __uint_as_float(((unsigned)h) << 16);
}

// truncation split: x ~= hi + lo, |err| <= 2^-16 |x|
__device__ __forceinline__ void split1(float x, unsigned short& h, unsigned short& l) {
    unsigned u = __float_as_uint(x);
    h = (unsigned short)(u >> 16);
    float r = x - __uint_as_float(u & 0xFFFF0000u);
    l = (unsigned short)(__float_as_uint(r) >> 16);
}
__device__ __forceinline__ void split4(f4 v, u16x4& h, u16x4& l) {
    unsigned short hh, ll;
    split1(v.x, hh, ll); h.x = hh; l.x = ll;
    split1(v.y, hh, ll); h.y = hh; l.y = ll;
    split1(v.z, hh, ll); h.z = hh; l.z = ll;
    split1(v.w, hh, ll); h.w = hh; l.w = ll;
}
// truncation hi only (for dead-lo paths; bit-identical hi to split4)
__device__ __forceinline__ u16x4 trunc4(f4 v) {
    u16x4 h;
    h.x = (unsigned short)(__float_as_uint(v.x) >> 16);
    h.y = (unsigned short)(__float_as_uint(v.y) >> 16);
    h.z = (unsigned short)(__float_as_uint(v.z) >> 16);
    h.w = (unsigned short)(__float_as_uint(v.w) >> 16);
    return h;
}

// Panel-tiled layout: [M/16][K/32] panels of 512 u16, panel = [gg 4][rr 16][ee 8].
__device__ __forceinline__ size_t toff4(int row, int c4, int kpan) {
    const int j = c4 & 31;
    return ((size_t)(row >> 4) * kpan + (c4 >> 5)) * 512
         + ((j & 15) >> 2) * 128 + (row & 15) * 8 + ((j >> 4) << 2);
}
__device__ __forceinline__ size_t toff1(int row, int k, int kpan) {
    const int j = k & 31;
    return ((size_t)(row >> 4) * kpan + (k >> 5)) * 512
         + ((j & 15) >> 2) * 128 + (row & 15) * 8 + ((j >> 4) << 2) + (j & 3);
}

__device__ __forceinline__ void gload16(const void* g, void* l) {
    __builtin_amdgcn_global_load_lds(
        (const __attribute__((address_space(1))) unsigned int*)g,
        (__attribute__((address_space(3))) unsigned int*)l, 16, 0, 0);
}

// ---------------- fused weight transpose + RNE split -> panel-tiled BT ----------------
struct WSeg { const float* W; unsigned short* Th; unsigned short* Tl;
              int K, N, kpan, tile0, tilesN; };
struct WAll { WSeg s[13]; };

__global__ __launch_bounds__(256) void wtrans_all(WAll all)
{
    const int bid = blockIdx.x;
    int si = 0;
    #pragma unroll
    for (int i = 1; i < 13; ++i) if (bid >= all.s[i].tile0) si = i;
    const WSeg sg = all.s[si];
    const int local = bid - sg.tile0;
    const int k0 = (local / sg.tilesN) * 32;
    const int n0 = (local % sg.tilesN) * 32;

    __shared__ float tile[32][33];
    const int t = threadIdx.x;
    const int r = t >> 3, c4 = (t & 7) * 4;
    f4 v = f4splat(0.0f);
    if (k0 + r < sg.K && n0 + c4 < sg.N)
        v = *(const f4*)(sg.W + (size_t)(k0 + r) * sg.N + n0 + c4);
    tile[r][c4 + 0] = v.x; tile[r][c4 + 1] = v.y;
    tile[r][c4 + 2] = v.z; tile[r][c4 + 3] = v.w;
    __syncthreads();
    {
        const int n = n0 + r;
        float x0 = tile[c4 + 0][r], x1 = tile[c4 + 1][r];
        float x2 = tile[c4 + 2][r], x3 = tile[c4 + 3][r];
        u16x4 hv, lv;
        hv.x = f2bf(x0); lv.x = f2bf(x0 - bf2f(hv.x));
        hv.y = f2bf(x1); lv.y = f2bf(x1 - bf2f(hv.y));
        hv.z = f2bf(x2); lv.z = f2bf(x2 - bf2f(hv.z));
        hv.w = f2bf(x3); lv.w = f2bf(x3 - bf2f(hv.w));
        const size_t off = toff4(n, k0 + c4, sg.kpan);
        *(u16x4*)(sg.Th + off) = hv;
        *(u16x4*)(sg.Tl + off) = lv;
    }
}

// context fp32 [1024][768] -> panel-tiled bf16-hi (lo dead: cond GEMM is nm=1)
__global__ __launch_bounds__(256) void ctx_split(
    const float* __restrict__ X, unsigned short* __restrict__ H)
{
    const int gid = blockIdx.x * 256 + threadIdx.x;   // 196608 f4 chunks
    const int row = gid / 192;
    const int c4 = (gid - row * 192) * 4;
    f4 v = *(const f4*)(X + (size_t)row * 768 + c4);
    const size_t off = toff4(row, c4, 24);
    *(u16x4*)(H + off) = trunc4(v);
}

// ---------------- elementwise prep (outputs panel-tiled bf16) ----------------
// xr/xa/xg: hi only (nm<=2 consumers never read act-lo). xw: split pair (w LoRA nm=3).
__global__ __launch_bounds__(256) void hs_lerp4(
    const float* __restrict__ hs,
    const float* __restrict__ x_r, const float* __restrict__ x_w,
    const float* __restrict__ x_a, const float* __restrict__ x_g,
    unsigned short* __restrict__ xr_h,
    unsigned short* __restrict__ xw_h, unsigned short* __restrict__ xw_l,
    unsigned short* __restrict__ xa_h,
    unsigned short* __restrict__ xg_h)
{
    const int gid = blockIdx.x * 256 + threadIdx.x;   // 1,048,576 f4 chunks
    const int c4 = (gid & 255) * 4;
    const int row = gid >> 8;
    const int tt = row & (T_ - 1);
    const f4 cur = *(const f4*)(hs + (size_t)row * H_ + c4);
    f4 prev = f4splat(0.0f);
    if (tt) prev = *(const f4*)(hs + (size_t)(row - 1) * H_ + c4);
    const f4 d = prev - cur;
    const size_t off = toff4(row, c4, 32);
    u16x4 h, l;
    *(u16x4*)(xr_h + off) = trunc4(cur + d * (*(const f4*)(x_r + c4)));
    split4(cur + d * (*(const f4*)(x_w + c4)), h, l);
    *(u16x4*)(xw_h + off) = h; *(u16x4*)(xw_l + off) = l;
    *(u16x4*)(xa_h + off) = trunc4(cur + d * (*(const f4*)(x_a + c4)));
    *(u16x4*)(xg_h + off) = trunc4(cur + d * (*(const f4*)(x_g + c4)));
}

__device__ __forceinline__ f4 ctx_sample(const float* __restrict__ cp, int b, int t, int c4) {
    const float scale = (float)(511.0 / 2047.0);
    float tf = (float)t * scale;
    int lo = (int)tf;
    float f = tf - (float)lo;
    int hi = lo + 1; if (hi > LCTX - 1) hi = LCTX - 1;
    f4 cl = *(const f4*)(cp + (size_t)(b * LCTX + lo) * 1024 + c4);
    f4 ch = *(const f4*)(cp + (size_t)(b * LCTX + hi) * 1024 + c4);
    return cl + (ch - cl) * f;
}

// xk/xv: hi only (k/v projections nm=1; LoRA vA consumer nm=1 — act-lo dead).
__global__ __launch_bounds__(256) void ctx_lerp2(
    const float* __restrict__ cp,
    const float* __restrict__ x_k, const float* __restrict__ x_v,
    unsigned short* __restrict__ xk_h,
    unsigned short* __restrict__ xv_h)
{
    const int gid = blockIdx.x * 256 + threadIdx.x;
    const int c4 = (gid & 255) * 4;
    const int row = gid >> 8;
    const int b = row >> 11;
    const int tt = row & (T_ - 1);
    const f4 cur = ctx_sample(cp, b, tt, c4);
    f4 prev = f4splat(0.0f);
    if (tt) prev = ctx_sample(cp, b, tt - 1, c4);
    const f4 d = prev - cur;
    const size_t off = toff4(row, c4, 32);
    *(u16x4*)(xk_h + off) = trunc4(cur + d * (*(const f4*)(x_k + c4)));
    *(u16x4*)(xv_h + off) = trunc4(cur + d * (*(const f4*)(x_v + c4)));
}

// ---------------- MFMA GEMM: 128x64 tile, batched segments, runtime epi ----------------
// nm==3: acc += Ah*Bh + Ah*Bl + Al*Bh (fp32-class).
// nm==2: acc += Ah*Bh + Ah*Bl (act bf16-hi; weights split).
// nm==1: acc += Ah*Bh (pure bf16).
struct GSeg {
    const unsigned short* ATh; const unsigned short* ATl;
    const unsigned short* BTh; const unsigned short* BTl;
    float* C; unsigned short* Ch; unsigned short* Cl;
    const float* bias; const float* aux1; const float* aux2;
    int K, N, kpanC, epi, nm;
};
struct GBatch { GSeg s[4]; };

template <int OSPLIT>
__global__ __launch_bounds__(256, 2) void mgemm(GBatch gb, int M)
{
    __shared__ __align__(16) unsigned short Ah_[8 * 512];
    __shared__ __align__(16) unsigned short Al_[8 * 512];
    __shared__ __align__(16) unsigned short Bh_[4 * 512];
    __shared__ __align__(16) unsigned short Bl_[4 * 512];
    const GSeg G = gb.s[blockIdx.z];
    const int bn = blockIdx.y * 64;
    if (bn >= G.N) return;
    const int K = G.K;
    const int kpan = K >> 5;
    const int tid = threadIdx.x;
    const int lane = tid & 63;
    const int wave = tid >> 6;
    const int bm = blockIdx.x * 128;
    const int g = lane >> 4, rr = lane & 15;
    const int sA0 = wave, sA1 = wave + 4;
    const int nm = G.nm;
    const bool full = (nm == 3);
    const bool wsplit = (nm >= 2);
    (void)M;

    f32x4 acc[4][2];
    #pragma unroll
    for (int mi = 0; mi < 4; ++mi)
        #pragma unroll
        for (int ni = 0; ni < 2; ++ni)
            acc[mi][ni] = (f32x4)(0.0f);

    const size_t aBase0 = (size_t)((bm >> 4) + sA0) * kpan * 512;
    const size_t aBase1 = (size_t)((bm >> 4) + sA1) * kpan * 512;
    const size_t bBase  = (size_t)((bn >> 4) + wave) * kpan * 512;

    for (int k0 = 0; k0 < K; k0 += 32) {
        const size_t kp = (size_t)(k0 >> 5) * 512 + (size_t)lane * 8;
        gload16(G.ATh + aBase0 + kp, &Ah_[sA0 * 512]);
        gload16(G.ATh + aBase1 + kp, &Ah_[sA1 * 512]);
        if (full) {
            gload16(G.ATl + aBase0 + kp, &Al_[sA0 * 512]);
            gload16(G.ATl + aBase1 + kp, &Al_[sA1 * 512]);
        }
        gload16(G.BTh + bBase + kp, &Bh_[wave * 512]);
        if (wsplit)
            gload16(G.BTl + bBase + kp, &Bl_[wave * 512]);
        __syncthreads();
        bf16x8 a_h[4], a_l[4], b_h[2], b_l[2];
        #pragma unroll
        for (int mi = 0; mi < 4; ++mi) {
            const int s = (wave >> 1) * 4 + mi;
            a_h[mi] = *(const bf16x8*)&Ah_[s * 512 + g * 128 + rr * 8];
        }
        if (full) {
            #pragma unroll
            for (int mi = 0; mi < 4; ++mi) {
                const int s = (wave >> 1) * 4 + mi;
                a_l[mi] = *(const bf16x8*)&Al_[s * 512 + g * 128 + rr * 8];
            }
        }
        #pragma unroll
        for (int ni = 0; ni < 2; ++ni) {
            const int s = (wave & 1) * 2 + ni;
            b_h[ni] = *(const bf16x8*)&Bh_[s * 512 + g * 128 + rr * 8];
        }
        if (wsplit) {
            #pragma unroll
            for (int ni = 0; ni < 2; ++ni) {
                const int s = (wave & 1) * 2 + ni;
                b_l[ni] = *(const bf16x8*)&Bl_[s * 512 + g * 128 + rr * 8];
            }
        }
        #pragma unroll
        for (int mi = 0; mi < 4; ++mi)
            #pragma unroll
            for (int ni = 0; ni < 2; ++ni)
                acc[mi][ni] = __builtin_amdgcn_mfma_f32_16x16x32_bf16(a_h[mi], b_h[ni], acc[mi][ni], 0, 0, 0);
        if (wsplit) {
            #pragma unroll
            for (int mi = 0; mi < 4; ++mi)
                #pragma unroll
                for (int ni = 0; ni < 2; ++ni)
                    acc[mi][ni] = __builtin_amdgcn_mfma_f32_16x16x32_bf16(a_h[mi], b_l[ni], acc[mi][ni], 0, 0, 0);
        }
        if (full) {
            #pragma unroll
            for (int mi = 0; mi < 4; ++mi)
                #pragma unroll
                for (int ni = 0; ni < 2; ++ni)
                    acc[mi][ni] = __builtin_amdgcn_mfma_f32_16x16x32_bf16(a_l[mi], b_h[ni], acc[mi][ni], 0, 0, 0);
        }
        __syncthreads();
    }
    const int wm = (wave >> 1) * 64;
    const int wn = (wave & 1) * 32;
    const int epi = G.epi;
    #pragma unroll
    for (int mi = 0; mi < 4; ++mi)
        #pragma unroll
        for (int ni = 0; ni < 2; ++ni)
            #pragma unroll
            for (int q = 0; q < 4; ++q) {
                const int grow = bm + wm + mi * 16 + g * 4 + q;
                const int gcol = bn + wn + ni * 16 + rr;
                float x = acc[mi][ni][q];
                if (epi == 1) x = -0.6065306597126334f * sgm(x + G.bias[gcol]);
                else if (epi == 2) x = sgm(x + G.bias[gcol]);
                else if (epi == 3) {
                    const size_t o3 = (size_t)grow * G.N + gcol;
                    float vt = G.aux1[o3];
                    x = vt + sgm(x + G.bias[gcol]) * (G.aux2[o3] - vt);
                }
                else if (epi == 4) x = tanhf(x);
                else if (epi == 5) x = sgm(x);
                if (OSPLIT) {
                    if (gcol < G.kpanC * 32) {
                        unsigned short hh, ll;
                        split1(x, hh, ll);
                        const size_t off = toff1(grow, gcol, G.kpanC);
                        G.Ch[off] = hh; G.Cl[off] = ll;
                    }
                } else {
                    G.C[(size_t)grow * G.N + gcol] = x;
                }
            }
}

// ---------------- dedicated pure-bf16 GEMM: 128x128 tile, BK=64 --------------------
// 8 gloads : 32 MFMA per iter (2x the 128x64 intensity); 2 barriers per 64-K.
// No launch-bounds min-waves cap (r18's spill cause); acc[4][4]+frags ~125 VGPR.
// Per-output-element MFMA accumulation chain identical to mgemm nm=1 -> bit-identical.
__global__ __launch_bounds__(256) void mgemm1(GBatch gb)
{
    __shared__ __align__(16) unsigned short Ah_[2 * 8 * 512];   // [khalf][panel][512]
    __shared__ __align__(16) unsigned short Bh_[2 * 8 * 512];
    const GSeg G = gb.s[blockIdx.z];
    const int bn = blockIdx.y * 128;
    if (bn >= G.N) return;
    const int K = G.K;
    const int kpan = K >> 5;
    const int lane = threadIdx.x & 63;
    const int wave = threadIdx.x >> 6;
    const int bm = blockIdx.x * 128;
    const int g = lane >> 4, rr = lane & 15;
    const int wr = wave >> 1, wc = wave & 1;

    f32x4 acc[4][4];
    #pragma unroll
    for (int mi = 0; mi < 4; ++mi)
        #pragma unroll
        for (int ni = 0; ni < 4; ++ni)
            acc[mi][ni] = (f32x4)(0.0f);

    // each wave stages A panels {2w,2w+1} and B panels {2w,2w+1}, both k-halves
    const size_t aB0 = (size_t)((bm >> 4) + 2 * wave) * kpan * 512;
    const size_t aB1 = (size_t)((bm >> 4) + 2 * wave + 1) * kpan * 512;
    const size_t bB0 = (size_t)((bn >> 4) + 2 * wave) * kpan * 512;
    const size_t bB1 = (size_t)((bn >> 4) + 2 * wave + 1) * kpan * 512;

    for (int k0 = 0; k0 < K; k0 += 64) {
        const size_t kp0 = (size_t)(k0 >> 5) * 512 + (size_t)lane * 8;
        const size_t kp1 = kp0 + 512;
        gload16(G.ATh + aB0 + kp0, &Ah_[(2 * wave) * 512]);
        gload16(G.ATh + aB1 + kp0, &Ah_[(2 * wave + 1) * 512]);
        gload16(G.ATh + aB0 + kp1, &Ah_[4096 + (2 * wave) * 512]);
        gload16(G.ATh + aB1 + kp1, &Ah_[4096 + (2 * wave + 1) * 512]);
        gload16(G.BTh + bB0 + kp0, &Bh_[(2 * wave) * 512]);
        gload16(G.BTh + bB1 + kp0, &Bh_[(2 * wave + 1) * 512]);
        gload16(G.BTh + bB0 + kp1, &Bh_[4096 + (2 * wave) * 512]);
        gload16(G.BTh + bB1 + kp1, &Bh_[4096 + (2 * wave + 1) * 512]);
        __syncthreads();
        #pragma unroll
        for (int p = 0; p < 2; ++p) {
            bf16x8 a_h[4], b_h[4];
            #pragma unroll
            for (int mi = 0; mi < 4; ++mi)
                a_h[mi] = *(const bf16x8*)&Ah_[p * 4096 + (wr * 4 + mi) * 512 + g * 128 + rr * 8];
            #pragma unroll
            for (int ni = 0; ni < 4; ++ni)
                b_h[ni] = *(const bf16x8*)&Bh_[p * 4096 + (wc * 4 + ni) * 512 + g * 128 + rr * 8];
            #pragma unroll
            for (int mi = 0; mi < 4; ++mi)
                #pragma unroll
                for (int ni = 0; ni < 4; ++ni)
                    acc[mi][ni] = __builtin_amdgcn_mfma_f32_16x16x32_bf16(a_h[mi], b_h[ni], acc[mi][ni], 0, 0, 0);
        }
        __syncthreads();
    }
    const int wm = wr * 64;
    const int wn = wc * 64;
    #pragma unroll
    for (int mi = 0; mi < 4; ++mi)
        #pragma unroll
        for (int ni = 0; ni < 4; ++ni)
            #pragma unroll
            for (int q = 0; q < 4; ++q) {
                const int grow = bm + wm + mi * 16 + g * 4 + q;
                const int gcol = bn + wn + ni * 16 + rr;
                G.C[(size_t)grow * G.N + gcol] = acc[mi][ni][q];
            }
}

// kk = normalize_per_head(k * k_k); k <- k * (1 + (a-1)*k_a)   (in place)
__global__ __launch_bounds__(256) void prep_k(
    float* __restrict__ k, const float* __restrict__ a,
    const float* __restrict__ k_k, const float* __restrict__ k_a,
    float* __restrict__ kk)
{
    const int gid = blockIdx.x * 256 + threadIdx.x;
    const int j = gid & 63;
    const int h = (gid >> 6) & (NH_ - 1);
    const int ch = h * 64 + j;
    const float kv = k[gid];
    float kkv = kv * k_k[ch];
    float ss = kkv * kkv;
    #pragma unroll
    for (int m = 32; m; m >>= 1) ss += __shfl_xor(ss, m, 64);
    const float nrm = fmaxf(sqrtf(ss), 1e-12f);
    kk[gid] = kkv / nrm;
    const float av = a[gid];
    k[gid] = kv * (1.0f + (av - 1.0f) * k_a[ch]);
}

// ---------------- Chunked RWKV7 scan (NC=64, CL=32) ----------------
// Phase A: 4-wave blocks; waves 0,1 = Q halves (cols 0-31 / 32-63);
// waves 2,3 = U halves. LDS stage + cross-wave partials.
__global__ __launch_bounds__(256, 1) void chunk_AU(
    const float* __restrict__ w, const float* __restrict__ k,
    const float* __restrict__ v, const float* __restrict__ kk,
    const float* __restrict__ a,
    float* __restrict__ Pbuf, float* __restrict__ Ubuf)
{
    const int bid = blockIdx.x;
    const int c = bid & (NC - 1);
    const int bh = bid >> 6;
    const int b = bh >> 4, h = bh & (NH_ - 1);
    const int tid = threadIdx.x;
    const int wv_ = tid >> 6;
    const int half = wv_ & 1;
    const bool isU = wv_ >= 2;
    const int lane = tid & 63;
    __shared__ __align__(16) float ew_s[64], ah_s[64], bh_s[64], kh_s[64], vh_s[64];
    __shared__ float part[4][64];

#define DECL_X(i) f4 x##i = f4splat(0.0f);
    REP8(DECL_X)
#undef DECL_X
    if (!isU) {
        const int local = lane - half * 32;
#define INIT_Q(i) \
        if (local == 4*i+0) x##i.x = 1.0f; \
        else if (local == 4*i+1) x##i.y = 1.0f; \
        else if (local == 4*i+2) x##i.z = 1.0f; \
        else if (local == 4*i+3) x##i.w = 1.0f;
        REP8(INIT_Q)
#undef INIT_Q
    }

    size_t idx = (((size_t)b * T_ + (size_t)c * CL) * NH_ + h) * 64 + lane;
    float wvv = 0, kkv = 0, av = 0, kv = 0, vvv = 0;
    if (wv_ == 0) { wvv = w[idx]; kkv = kk[idx]; av = a[idx]; }
    else if (wv_ == 1) { kv = k[idx]; vvv = v[idx]; }

    for (int t = 0; t < CL; ++t) {
        if (wv_ == 0) {
            ew_s[lane] = expf(wvv);
            ah_s[lane] = -kkv;
            bh_s[lane] = kkv * av;
        } else if (wv_ == 1) {
            kh_s[lane] = kv;
            vh_s[lane] = vvv;
        }
        __syncthreads();                                   // b1: stage ready
        if (t + 1 < CL) {
            idx += NH_ * 64;
            if (wv_ == 0) { wvv = w[idx]; kkv = kk[idx]; av = a[idx]; }
            else if (wv_ == 1) { kv = k[idx]; vvv = v[idx]; }
        }
        const f4* A4 = (const f4*)ah_s + half * 8;
        f4 da = f4splat(0.0f);
#define DOT_(i) { da += x##i * A4[i]; }
        REP8(DOT_)
#undef DOT_
        part[wv_][lane] = hsum4(da);
        __syncthreads();                                   // b2: partials ready
        const float D = isU ? part[2][lane] + part[3][lane]
                            : part[0][lane] + part[1][lane];
        const float vcur = vh_s[lane];
        const f4* E4 = (const f4*)ew_s + half * 8;
        const f4* B4 = (const f4*)bh_s + half * 8;
        const f4* K4 = (const f4*)kh_s + half * 8;
        if (!isU) {
#define UPDQ_(i) { x##i = x##i * E4[i] + D * B4[i]; }
            REP8(UPDQ_)
#undef UPDQ_
        } else {
#define UPDU_(i) { x##i = x##i * E4[i] + D * B4[i] + vcur * K4[i]; }
            REP8(UPDU_)
#undef UPDU_
        }
        __syncthreads();                                   // b3: end of step
    }
    float* Dst = (isU ? Ubuf : Pbuf)
               + (((size_t)bh * NC + c) * 64 + lane) * 64 + half * 32;
#define ST_(i) ((f4*)Dst)[i] = x##i;
    REP8(ST_)
#undef ST_
}

// Phase B: barrier-free register-resident chunk scan.
__global__ __launch_bounds__(64) void chunk_scan(
    const float* __restrict__ Pbuf, float* __restrict__ USbuf)
{
    const int wg = (blockIdx.x & 7) * 64 + (blockIdx.x >> 3);
    const int bh = wg >> 4;
    const int rg = wg & 15;
    const int j = threadIdx.x;
    const int r0 = rg * 4;

    float a0 = 0, a1 = 0, a2 = 0, a3 = 0;
    float u0, u1, u2, u3;
    float pA[64], pB[64];

    const size_t base = (size_t)bh * NC * 4096;
    {
        const float* Pb = Pbuf + base + j;
        #pragma unroll
        for (int k2 = 0; k2 < 64; ++k2) pA[k2] = Pb[k2 * 64];
        const float* Ub = USbuf + base + r0 * 64 + j;
        u0 = Ub[0]; u1 = Ub[64]; u2 = Ub[128]; u3 = Ub[192];
    }

#define SCAN_STEP(PC, PN, c) { \
    float n0 = u0, n1 = u1, n2 = u2, n3 = u3; \
    float* Ub = USbuf + base + (size_t)(c) * 4096 + r0 * 64 + j; \
    Ub[0] = a0; Ub[64] = a1; Ub[128] = a2; Ub[192] = a3; \
    if ((c) + 1 < NC) { \
        const float* Un = USbuf + base + (size_t)((c) + 1) * 4096 + r0 * 64 + j; \
        u0 = Un[0]; u1 = Un[64]; u2 = Un[128]; u3 = Un[192]; \
        const float* Pn = Pbuf + base + (size_t)((c) + 1) * 4096 + j; \
        _Pragma("unroll") \
        for (int k2 = 0; k2 < 64; ++k2) PN[k2] = Pn[k2 * 64]; \
    } \
    _Pragma("unroll") \
    for (int k2 = 0; k2 < 64; ++k2) { \
        const float s0 = rdlane(a0, k2), s1 = rdlane(a1, k2); \
        const float s2 = rdlane(a2, k2), s3 = rdlane(a3, k2); \
        n0 += s0 * PC[k2]; n1 += s1 * PC[k2]; \
        n2 += s2 * PC[k2]; n3 += s3 * PC[k2]; \
    } \
    a0 = n0; a1 = n1; a2 = n2; a3 = n3; }

    for (int c = 0; c < NC; c += 2) {
        SCAN_STEP(pA, pB, c)
        SCAN_STEP(pB, pA, c + 1)
    }
#undef SCAN_STEP
}

// Phase C + fused GroupNorm/readout/gate: one wave per (bh,c); S register-resident
// (lane = value-dim row). og written as bf16-hi only (out-projection is nm=1).
__global__ __launch_bounds__(256) void chunk_out_fused(
    const float* __restrict__ r, const float* __restrict__ w,
    const float* __restrict__ k, const float* __restrict__ v,
    const float* __restrict__ kk, const float* __restrict__ a,
    const float* __restrict__ Scbuf, const float* __restrict__ g,
    const float* __restrict__ r_k, const float* __restrict__ gn_w,
    const float* __restrict__ gn_b,
    unsigned short* __restrict__ og_h)
{
    const int gw = blockIdx.x * 4 + (threadIdx.x >> 6);   // 0..2047
    const int c = gw & (NC - 1);
    const int bh = gw >> 6;
    const int b = bh >> 4, h = bh & (NH_ - 1);
    const int lane = threadIdx.x & 63;
    const int ch = h * 64 + lane;
    const float rk_c = r_k[ch];
    const float gnw_c = gn_w[ch];
    const float gnb_c = gn_b[ch];

    float s[64];
    {
        const float* Srow = Scbuf + (((size_t)bh * NC + c) * 64 + lane) * 64;
        #pragma unroll
        for (int j = 0; j < 64; ++j) s[j] = Srow[j];
    }

    size_t idx = (((size_t)b * T_ + (size_t)c * CL) * NH_ + h) * 64 + lane;
    int rowTok = b * T_ + c * CL;
    float wv = w[idx], kkv = kk[idx], av = a[idx], kv = k[idx], rv = r[idx],
          vv = v[idx], gv = g[idx];

    for (int t = 0; t < CL; ++t) {
        const float e_own = expf(wv);
        const float ah_own = -kkv;
        const float bh_own = kkv * av;
        const float k_own = kv;
        const float r_own = rv;
        const float v_own = vv;
        const float g_own = gv;
        if (t + 1 < CL) {
            idx += NH_ * 64;
            wv = w[idx]; kkv = kk[idx]; av = a[idx]; kv = k[idx]; rv = r[idx];
            vv = v[idx]; gv = g[idx];
        }
        float d0 = 0, d1 = 0, d2 = 0, d3 = 0;
        #pragma unroll
        for (int j = 0; j < 64; j += 4) {
            d0 += s[j]     * rdlane(ah_own, j);
            d1 += s[j + 1] * rdlane(ah_own, j + 1);
            d2 += s[j + 2] * rdlane(ah_own, j + 2);
            d3 += s[j + 3] * rdlane(ah_own, j + 3);
        }
        const float sa = (d0 + d1) + (d2 + d3);
        float o0 = 0, o1 = 0, o2 = 0, o3 = 0;
        #pragma unroll
        for (int j = 0; j < 64; j += 4) {
            {
                const float ej = rdlane(e_own, j), bj = rdlane(bh_own, j);
                const float kj = rdlane(k_own, j), rj = rdlane(r_own, j);
                s[j] = s[j] * ej + sa * bj + v_own * kj; o0 += s[j] * rj;
            }
            {
                const float ej = rdlane(e_own, j + 1), bj = rdlane(bh_own, j + 1);
                const float kj = rdlane(k_own, j + 1), rj = rdlane(r_own, j + 1);
                s[j + 1] = s[j + 1] * ej + sa * bj + v_own * kj; o1 += s[j + 1] * rj;
            }
            {
                const float ej = rdlane(e_own, j + 2), bj = rdlane(bh_own, j + 2);
                const float kj = rdlane(k_own, j + 2), rj = rdlane(r_own, j + 2);
                s[j + 2] = s[j + 2] * ej + sa * bj + v_own * kj; o2 += s[j + 2] * rj;
            }
            {
                const float ej = rdlane(e_own, j + 3), bj = rdlane(bh_own, j + 3);
                const float kj = rdlane(k_own, j + 3), rj = rdlane(r_own, j + 3);
                s[j + 3] = s[j + 3] * ej + sa * bj + v_own * kj; o3 += s[j + 3] * rj;
            }
        }
        const float ov = (o0 + o1) + (o2 + o3);
        // fused GroupNorm(64) + r_k readout + output gate
        float s1r = ov, s2r = ov * ov, term = r_own * k_own * rk_c;
        #pragma unroll
        for (int m = 32; m; m >>= 1) {
            s1r += __shfl_xor(s1r, m, 64);
            s2r += __shfl_xor(s2r, m, 64);
            term += __shfl_xor(term, m, 64);
        }
        const float mu = s1r * (1.0f / 64.0f);
        const float var = s2r * (1.0f / 64.0f) - mu * mu;
        const float on = (ov - mu) * rsqrtf(var + 6.4e-4f);
        const float outv = (on * gnw_c + gnb_c + term * v_own) * g_own;
        og_h[toff1(rowTok, ch, 32)] =
            (unsigned short)(__float_as_uint(outv) >> 16);
        ++rowTok;
    }
}

extern "C" void kernel_launch(void* const* d_in, const int* in_sizes, int n_in,
                              void* d_out, int out_size, void* d_ws, size_t ws_size,
                              hipStream_t stream)
{
    const float* hs      = (const float*)d_in[0];
    const float* context = (const float*)d_in[1];
    const float* v_first = (const float*)d_in[2];
    const float* x_r = (const float*)d_in[3];
    const float* x_w = (const float*)d_in[4];
    const float* x_k = (const float*)d_in[5];
    const float* x_v = (const float*)d_in[6];
    const float* x_a = (const float*)d_in[7];
    const float* x_g = (const float*)d_in[8];
    const float* k_k = (const float*)d_in[9];
    const float* k_a = (const float*)d_in[10];
    const float* r_k = (const float*)d_in[11];
    const float* W_r = (const float*)d_in[12];
    const float* W_k = (const float*)d_in[13];
    const float* W_v = (const float*)d_in[14];
    const float* W_o = (const float*)d_in[15];
    const float* W_cond = (const float*)d_in[16];
    const float* wA = (const float*)d_in[17];
    const float* wB = (const float*)d_in[18];
    const float* wb = (const float*)d_in[19];
    const float* aA = (const float*)d_in[20];
    const float* aB = (const float*)d_in[21];
    const float* ab = (const float*)d_in[22];
    const float* gA = (const float*)d_in[23];
    const float* gB = (const float*)d_in[24];
    const float* vA = (const float*)d_in[25];
    const float* vB = (const float*)d_in[26];
    const float* vb = (const float*)d_in[27];
    const float* gn_w = (const float*)d_in[28];
    const float* gn_b = (const float*)d_in[29];
    (void)in_sizes; (void)n_in; (void)out_size; (void)ws_size;

    float* ws = (float*)d_ws;
    float* cp    = ws;                   // [1024,1024] f32
    float* rbuf  = cp    + (1 << 20);
    float* kbuf  = rbuf  + (4 << 20);
    float* vtmp  = kbuf  + (4 << 20);    // raw v
    float* wbuf  = vtmp  + (4 << 20);    // log-decay w
    float* abuf  = wbuf  + (4 << 20);
    float* obuf  = abuf  + (4 << 20);    // alias xr hi; later og hi
    float* kkbuf = obuf  + (4 << 20);    // alias xg hi
    float* gbuf  = kkbuf + (4 << 20);    // alias xk hi
    float* vbuf  = gbuf  + (4 << 20);    // alias xv hi
    float* Pbuf  = vbuf  + (4 << 20);    // 8M; xw pair aliases
    float* Ubuf  = Pbuf  + (8 << 20);    // 8M: U then in-place chunk-start states; xa hi aliases
    float* endf  = Ubuf  + (8 << 20);

    unsigned short* xr_h = (unsigned short*)obuf;
    unsigned short* xw_h = (unsigned short*)Pbuf;  unsigned short* xw_l = xw_h + (4 << 20);
    unsigned short* xa_h = (unsigned short*)Ubuf;
    unsigned short* xg_h = (unsigned short*)kkbuf;
    unsigned short* xk_h = (unsigned short*)gbuf;
    unsigned short* xv_h = (unsigned short*)vbuf;
    // og hi lives in the obuf region (xr hi dead after r-projection)
    unsigned short* og_h = (unsigned short*)obuf;

    unsigned short* u = (unsigned short*)endf;
    unsigned short* ctx_h = u;  u += 786432;
    unsigned short* w1h = u;    u += 262144;
    unsigned short* w1l = u;    u += 262144;
    unsigned short* a1h = u;    u += 262144;
    unsigned short* a1l = u;    u += 262144;
    unsigned short* g1h = u;    u += 524288;
    unsigned short* g1l = u;    u += 524288;
    unsigned short* v1h = u;    u += 131072;
    unsigned short* v1l = u;    u += 131072;
    unsigned short* condT_h = u; u += 786432;
    unsigned short* condT_l = u; u += 786432;
    unsigned short* rT_h = u;    u += 1048576;
    unsigned short* rT_l = u;    u += 1048576;
    unsigned short* kT_h = u;    u += 1048576;
    unsigned short* kT_l = u;    u += 1048576;
    unsigned short* vT_h = u;    u += 1048576;
    unsigned short* vT_l = u;    u += 1048576;
    unsigned short* oT_h = u;    u += 1048576;
    unsigned short* oT_l = u;    u += 1048576;
    unsigned short* waT_h = u;   u += 65536;
    unsigned short* waT_l = u;   u += 65536;
    unsigned short* wbT_h = u;   u += 65536;
    unsigned short* wbT_l = u;   u += 65536;
    unsigned short* aaT_h = u;   u += 65536;
    unsigned short* aaT_l = u;   u += 65536;
    unsigned short* abT_h = u;   u += 65536;
    unsigned short* abT_l = u;   u += 65536;
    unsigned short* gaT_h = u;   u += 131072;
    unsigned short* gaT_l = u;   u += 131072;
    unsigned short* gbT_h = u;   u += 131072;
    unsigned short* gbT_l = u;   u += 131072;
    unsigned short* vaT_h = u;   u += 65536;   // N padded 16->64
    unsigned short* vaT_l = u;   u += 65536;
    unsigned short* vbT_h = u;   u += 32768;   // K padded 16->32
    unsigned short* vbT_l = u;   u += 32768;

    const dim3 blk(256);
    // ---- fused weight transposes + RNE split -> panel-tiled (padded) ----
    {
        WAll all;
        auto seg = [](const float* W, unsigned short* Th, unsigned short* Tl,
                      int K, int N, int Kpad, int Npad, int tile0) {
            WSeg s; s.W = W; s.Th = Th; s.Tl = Tl; s.K = K; s.N = N;
            s.kpan = Kpad / 32; s.tile0 = tile0; s.tilesN = Npad / 32; return s;
        };
        int t0 = 0;
        all.s[0]  = seg(W_cond, condT_h, condT_l, 768, 1024, 768, 1024, t0);  t0 += 24 * 32;
        all.s[1]  = seg(W_r, rT_h, rT_l, 1024, 1024, 1024, 1024, t0);         t0 += 32 * 32;
        all.s[2]  = seg(W_k, kT_h, kT_l, 1024, 1024, 1024, 1024, t0);         t0 += 32 * 32;
        all.s[3]  = seg(W_v, vT_h, vT_l, 1024, 1024, 1024, 1024, t0);         t0 += 32 * 32;
        all.s[4]  = seg(W_o, oT_h, oT_l, 1024, 1024, 1024, 1024, t0);         t0 += 32 * 32;
        all.s[5]  = seg(wA, waT_h, waT_l, 1024, 64, 1024, 64, t0);            t0 += 32 * 2;
        all.s[6]  = seg(wB, wbT_h, wbT_l, 64, 1024, 64, 1024, t0);            t0 += 2 * 32;
        all.s[7]  = seg(aA, aaT_h, aaT_l, 1024, 64, 1024, 64, t0);            t0 += 32 * 2;
        all.s[8]  = seg(aB, abT_h, abT_l, 64, 1024, 64, 1024, t0);            t0 += 2 * 32;
        all.s[9]  = seg(gA, gaT_h, gaT_l, 1024, 128, 1024, 128, t0);          t0 += 32 * 4;
        all.s[10] = seg(gB, gbT_h, gbT_l, 128, 1024, 128, 1024, t0);          t0 += 4 * 32;
        all.s[11] = seg(vA, vaT_h, vaT_l, 1024, 16, 1024, 64, t0);            t0 += 32 * 2;
        all.s[12] = seg(vB, vbT_h, vbT_l, 16, 1024, 32, 1024, t0);            t0 += 1 * 32;
        wtrans_all<<<dim3(t0), blk, 0, stream>>>(all);
    }

    auto GS = [](const unsigned short* ah, const unsigned short* al,
                 const unsigned short* bh, const unsigned short* bl,
                 float* c, unsigned short* ch, unsigned short* cl,
                 int K, int N, int kpanC, int epi, int nm,
                 const float* bias, const float* a1, const float* a2) {
        GSeg s; s.ATh = ah; s.ATl = al; s.BTh = bh; s.BTl = bl;
        s.C = c; s.Ch = ch; s.Cl = cl; s.bias = bias; s.aux1 = a1; s.aux2 = a2;
        s.K = K; s.N = N; s.kpanC = kpanC; s.epi = epi; s.nm = nm; return s;
    };

    // ---- activations (panel-tiled pre-split) ----
    ctx_split<<<dim3(768), blk, 0, stream>>>(context, ctx_h);
    hs_lerp4<<<dim3(4096), blk, 0, stream>>>(hs, x_r, x_w, x_a, x_g,
                                             xr_h, xw_h, xw_l, xa_h, xg_h);
    {
        GBatch gb;
        gb.s[0] = GS(ctx_h, nullptr, condT_h, nullptr, cp, nullptr, nullptr,
                     768, 1024, 0, 0, 1, nullptr, nullptr, nullptr);
        gb.s[1] = gb.s[0]; gb.s[2] = gb.s[0]; gb.s[3] = gb.s[0];
        mgemm1<<<dim3(8, 8, 1), blk, 0, stream>>>(gb);
    }
    ctx_lerp2<<<dim3(4096), blk, 0, stream>>>(cp, x_k, x_v, xk_h, xv_h);

    // ---- main projections r/k/v batched over grid.z (pure bf16, 128x128 BK=64) ----
    {
        GBatch gb;
        gb.s[0] = GS(xr_h, nullptr, rT_h, nullptr, rbuf, nullptr, nullptr,
                     1024, 1024, 0, 0, 1, nullptr, nullptr, nullptr);
        gb.s[1] = GS(xk_h, nullptr, kT_h, nullptr, kbuf, nullptr, nullptr,
                     1024, 1024, 0, 0, 1, nullptr, nullptr, nullptr);
        gb.s[2] = GS(xv_h, nullptr, vT_h, nullptr, vtmp, nullptr, nullptr,
                     1024, 1024, 0, 0, 1, nullptr, nullptr, nullptr);
        gb.s[3] = gb.s[0];
        mgemm1<<<dim3(32, 8, 3), blk, 0, stream>>>(gb);
    }
    // ---- LoRA stage 1: 4 GEMMs in one z-batched launch (panel-tiled outputs).
    // w stays nm=3 (decay exp-compounds); a/g/v sigmoid-damped -> nm=1. ----
    {
        GBatch gb;
        gb.s[0] = GS(xw_h, xw_l, waT_h, waT_l, nullptr, w1h, w1l,
                     1024, 64, 2, 4, 3, nullptr, nullptr, nullptr);
        gb.s[1] = GS(xa_h, nullptr, aaT_h, nullptr, nullptr, a1h, a1l,
                     1024, 64, 2, 0, 1, nullptr, nullptr, nullptr);
        gb.s[2] = GS(xg_h, nullptr, gaT_h, nullptr, nullptr, g1h, g1l,
                     1024, 128, 4, 5, 1, nullptr, nullptr, nullptr);
        gb.s[3] = GS(xv_h, nullptr, vaT_h, nullptr, nullptr, v1h, v1l,
                     1024, 64, 1, 0, 1, nullptr, nullptr, nullptr);
        mgemm<1><<<dim3(32, 2, 4), blk, 0, stream>>>(gb, 4096);
    }
    // ---- LoRA stage 2: 4 GEMMs in one z-batched launch (all nm=3: tiny K) ----
    {
        GBatch gb;
        gb.s[0] = GS(w1h, w1l, wbT_h, wbT_l, wbuf, nullptr, nullptr,
                     64, 1024, 0, 1, 3, wb, nullptr, nullptr);
        gb.s[1] = GS(a1h, a1l, abT_h, abT_l, abuf, nullptr, nullptr,
                     64, 1024, 0, 2, 3, ab, nullptr, nullptr);
        gb.s[2] = GS(g1h, g1l, gbT_h, gbT_l, gbuf, nullptr, nullptr,
                     128, 1024, 0, 0, 3, nullptr, nullptr, nullptr);
        gb.s[3] = GS(v1h, v1l, vbT_h, vbT_l, vbuf, nullptr, nullptr,
                     32, 1024, 0, 3, 3, vb, vtmp, v_first);
        mgemm<0><<<dim3(32, 16, 4), blk, 0, stream>>>(gb, 4096);
    }

    // ---- recurrence ----
    prep_k<<<dim3(16384), blk, 0, stream>>>(kbuf, abuf, k_k, k_a, kkbuf);
    chunk_AU<<<dim3(2048), dim3(256), 0, stream>>>(wbuf, kbuf, vbuf, kkbuf, abuf, Pbuf, Ubuf);
    chunk_scan<<<dim3(512), dim3(64), 0, stream>>>(Pbuf, Ubuf);
    chunk_out_fused<<<dim3(512), dim3(256), 0, stream>>>(rbuf, wbuf, kbuf, vbuf, kkbuf, abuf,
                                                         Ubuf, gbuf, r_k, gn_w, gn_b, og_h);

    // ---- output projection (pure bf16, 128x128 BK=64) ----
    {
        GBatch gb;
        gb.s[0] = GS(og_h, nullptr, oT_h, nullptr, (float*)d_out, nullptr, nullptr,
                     1024, 1024, 0, 0, 1, nullptr, nullptr, nullptr);
        gb.s[1] = gb.s[0]; gb.s[2] = gb.s[0]; gb.s[3] = gb.s[0];
        mgemm1<<<dim3(32, 8, 1), blk, 0, stream>>>(gb);
    }
}

// Round 28
// 507.347 us; speedup vs baseline: 1.0195x; 1.0195x over previous
//
#include <hip/hip_runtime.h>
#include <cstddef>
#include <cstdint>

#define T_ 2048
#define H_ 1024
#define NH_ 16
#define LCTX 512
#define NC 64     // number of chunks
#define CL 32     // chunk length (NC*CL == T_)

typedef __attribute__((ext_vector_type(4))) float f4;
typedef __attribute__((ext_vector_type(4))) unsigned short u16x4;
typedef __attribute__((ext_vector_type(8))) short bf16x8;
typedef __attribute__((ext_vector_type(4))) float f32x4;

#define REP8(X) X(0) X(1) X(2) X(3) X(4) X(5) X(6) X(7)

__device__ __forceinline__ float sgm(float x) { return 1.0f / (1.0f + expf(-x)); }
__device__ __forceinline__ f4 f4splat(float v) { f4 r; r.x = v; r.y = v; r.z = v; r.w = v; return r; }
__device__ __forceinline__ float hsum4(f4 v) { return (v.x + v.y) + (v.z + v.w); }

__device__ __forceinline__ float rdlane(float v, int l) {
    return __uint_as_float(__builtin_amdgcn_readlane(__float_as_uint(v), l));
}

__device__ __forceinline__ unsigned short f2bf(float x) {   // RNE (weights, one-time)
    unsigned u = __float_as_uint(x);
    u += 0x7FFFu + ((u >> 16) & 1u);
    return (unsigned short)(u >> 16);
}
__device__ __forceinline__ float bf2f(unsigned short h) {
    return __uint_as_float(((unsigned)h) << 16);
}

// truncation split: x ~= hi + lo, |err| <= 2^-16 |x|
__device__ __forceinline__ void split1(float x, unsigned short& h, unsigned short& l) {
    unsigned u = __float_as_uint(x);
    h = (unsigned short)(u >> 16);
    float r = x - __uint_as_float(u & 0xFFFF0000u);
    l = (unsigned short)(__float_as_uint(r) >> 16);
}
__device__ __forceinline__ void split4(f4 v, u16x4& h, u16x4& l) {
    unsigned short hh, ll;
    split1(v.x, hh, ll); h.x = hh; l.x = ll;
    split1(v.y, hh, ll); h.y = hh; l.y = ll;
    split1(v.z, hh, ll); h.z = hh; l.z = ll;
    split1(v.w, hh, ll); h.w = hh; l.w = ll;
}
// truncation hi only (for dead-lo paths; bit-identical hi to split4)
__device__ __forceinline__ u16x4 trunc4(f4 v) {
    u16x4 h;
    h.x = (unsigned short)(__float_as_uint(v.x) >> 16);
    h.y = (unsigned short)(__float_as_uint(v.y) >> 16);
    h.z = (unsigned short)(__float_as_uint(v.z) >> 16);
    h.w = (unsigned short)(__float_as_uint(v.w) >> 16);
    return h;
}

// Panel-tiled layout: [M/16][K/32] panels of 512 u16, panel = [gg 4][rr 16][ee 8].
__device__ __forceinline__ size_t toff4(int row, int c4, int kpan) {
    const int j = c4 & 31;
    return ((size_t)(row >> 4) * kpan + (c4 >> 5)) * 512
         + ((j & 15) >> 2) * 128 + (row & 15) * 8 + ((j >> 4) << 2);
}
__device__ __forceinline__ size_t toff1(int row, int k, int kpan) {
    const int j = k & 31;
    return ((size_t)(row >> 4) * kpan + (k >> 5)) * 512
         + ((j & 15) >> 2) * 128 + (row & 15) * 8 + ((j >> 4) << 2) + (j & 3);
}

__device__ __forceinline__ void gload16(const void* g, void* l) {
    __builtin_amdgcn_global_load_lds(
        (const __attribute__((address_space(1))) unsigned int*)g,
        (__attribute__((address_space(3))) unsigned int*)l, 16, 0, 0);
}

// ---------------- fused weight transpose + RNE split -> panel-tiled BT ----------------
struct WSeg { const float* W; unsigned short* Th; unsigned short* Tl;
              int K, N, kpan, tile0, tilesN; };
struct WAll { WSeg s[13]; };

__global__ __launch_bounds__(256) void wtrans_all(WAll all)
{
    const int bid = blockIdx.x;
    int si = 0;
    #pragma unroll
    for (int i = 1; i < 13; ++i) if (bid >= all.s[i].tile0) si = i;
    const WSeg sg = all.s[si];
    const int local = bid - sg.tile0;
    const int k0 = (local / sg.tilesN) * 32;
    const int n0 = (local % sg.tilesN) * 32;

    __shared__ float tile[32][33];
    const int t = threadIdx.x;
    const int r = t >> 3, c4 = (t & 7) * 4;
    f4 v = f4splat(0.0f);
    if (k0 + r < sg.K && n0 + c4 < sg.N)
        v = *(const f4*)(sg.W + (size_t)(k0 + r) * sg.N + n0 + c4);
    tile[r][c4 + 0] = v.x; tile[r][c4 + 1] = v.y;
    tile[r][c4 + 2] = v.z; tile[r][c4 + 3] = v.w;
    __syncthreads();
    {
        const int n = n0 + r;
        float x0 = tile[c4 + 0][r], x1 = tile[c4 + 1][r];
        float x2 = tile[c4 + 2][r], x3 = tile[c4 + 3][r];
        u16x4 hv, lv;
        hv.x = f2bf(x0); lv.x = f2bf(x0 - bf2f(hv.x));
        hv.y = f2bf(x1); lv.y = f2bf(x1 - bf2f(hv.y));
        hv.z = f2bf(x2); lv.z = f2bf(x2 - bf2f(hv.z));
        hv.w = f2bf(x3); lv.w = f2bf(x3 - bf2f(hv.w));
        const size_t off = toff4(n, k0 + c4, sg.kpan);
        *(u16x4*)(sg.Th + off) = hv;
        *(u16x4*)(sg.Tl + off) = lv;
    }
}

// context fp32 [1024][768] -> panel-tiled bf16-hi (lo dead: cond GEMM is nm=1)
__global__ __launch_bounds__(256) void ctx_split(
    const float* __restrict__ X, unsigned short* __restrict__ H)
{
    const int gid = blockIdx.x * 256 + threadIdx.x;   // 196608 f4 chunks
    const int row = gid / 192;
    const int c4 = (gid - row * 192) * 4;
    f4 v = *(const f4*)(X + (size_t)row * 768 + c4);
    const size_t off = toff4(row, c4, 24);
    *(u16x4*)(H + off) = trunc4(v);
}

// ---------------- elementwise prep (outputs panel-tiled bf16) ----------------
// xr/xa/xg: hi only (nm<=2 consumers never read act-lo). xw: split pair (w LoRA nm=3).
__global__ __launch_bounds__(256) void hs_lerp4(
    const float* __restrict__ hs,
    const float* __restrict__ x_r, const float* __restrict__ x_w,
    const float* __restrict__ x_a, const float* __restrict__ x_g,
    unsigned short* __restrict__ xr_h,
    unsigned short* __restrict__ xw_h, unsigned short* __restrict__ xw_l,
    unsigned short* __restrict__ xa_h,
    unsigned short* __restrict__ xg_h)
{
    const int gid = blockIdx.x * 256 + threadIdx.x;   // 1,048,576 f4 chunks
    const int c4 = (gid & 255) * 4;
    const int row = gid >> 8;
    const int tt = row & (T_ - 1);
    const f4 cur = *(const f4*)(hs + (size_t)row * H_ + c4);
    f4 prev = f4splat(0.0f);
    if (tt) prev = *(const f4*)(hs + (size_t)(row - 1) * H_ + c4);
    const f4 d = prev - cur;
    const size_t off = toff4(row, c4, 32);
    u16x4 h, l;
    *(u16x4*)(xr_h + off) = trunc4(cur + d * (*(const f4*)(x_r + c4)));
    split4(cur + d * (*(const f4*)(x_w + c4)), h, l);
    *(u16x4*)(xw_h + off) = h; *(u16x4*)(xw_l + off) = l;
    *(u16x4*)(xa_h + off) = trunc4(cur + d * (*(const f4*)(x_a + c4)));
    *(u16x4*)(xg_h + off) = trunc4(cur + d * (*(const f4*)(x_g + c4)));
}

__device__ __forceinline__ f4 ctx_sample(const float* __restrict__ cp, int b, int t, int c4) {
    const float scale = (float)(511.0 / 2047.0);
    float tf = (float)t * scale;
    int lo = (int)tf;
    float f = tf - (float)lo;
    int hi = lo + 1; if (hi > LCTX - 1) hi = LCTX - 1;
    f4 cl = *(const f4*)(cp + (size_t)(b * LCTX + lo) * 1024 + c4);
    f4 ch = *(const f4*)(cp + (size_t)(b * LCTX + hi) * 1024 + c4);
    return cl + (ch - cl) * f;
}

// xk/xv: hi only (k/v projections nm=1; LoRA vA consumer nm=1 — act-lo dead).
__global__ __launch_bounds__(256) void ctx_lerp2(
    const float* __restrict__ cp,
    const float* __restrict__ x_k, const float* __restrict__ x_v,
    unsigned short* __restrict__ xk_h,
    unsigned short* __restrict__ xv_h)
{
    const int gid = blockIdx.x * 256 + threadIdx.x;
    const int c4 = (gid & 255) * 4;
    const int row = gid >> 8;
    const int b = row >> 11;
    const int tt = row & (T_ - 1);
    const f4 cur = ctx_sample(cp, b, tt, c4);
    f4 prev = f4splat(0.0f);
    if (tt) prev = ctx_sample(cp, b, tt - 1, c4);
    const f4 d = prev - cur;
    const size_t off = toff4(row, c4, 32);
    *(u16x4*)(xk_h + off) = trunc4(cur + d * (*(const f4*)(x_k + c4)));
    *(u16x4*)(xv_h + off) = trunc4(cur + d * (*(const f4*)(x_v + c4)));
}

// ---------------- MFMA GEMM: 128x64 tile, batched segments, runtime epi ----------------
// nm==3: acc += Ah*Bh + Ah*Bl + Al*Bh (fp32-class).
// nm==2: acc += Ah*Bh + Ah*Bl (act bf16-hi; weights split).
// nm==1: acc += Ah*Bh (pure bf16).
struct GSeg {
    const unsigned short* ATh; const unsigned short* ATl;
    const unsigned short* BTh; const unsigned short* BTl;
    float* C; unsigned short* Ch; unsigned short* Cl;
    const float* bias; const float* aux1; const float* aux2;
    int K, N, kpanC, epi, nm;
};
struct GBatch { GSeg s[4]; };

template <int OSPLIT>
__global__ __launch_bounds__(256, 2) void mgemm(GBatch gb, int M)
{
    __shared__ __align__(16) unsigned short Ah_[8 * 512];
    __shared__ __align__(16) unsigned short Al_[8 * 512];
    __shared__ __align__(16) unsigned short Bh_[4 * 512];
    __shared__ __align__(16) unsigned short Bl_[4 * 512];
    const GSeg G = gb.s[blockIdx.z];
    const int bn = blockIdx.y * 64;
    if (bn >= G.N) return;
    const int K = G.K;
    const int kpan = K >> 5;
    const int tid = threadIdx.x;
    const int lane = tid & 63;
    const int wave = tid >> 6;
    const int bm = blockIdx.x * 128;
    const int g = lane >> 4, rr = lane & 15;
    const int sA0 = wave, sA1 = wave + 4;
    const int nm = G.nm;
    const bool full = (nm == 3);
    const bool wsplit = (nm >= 2);
    (void)M;

    f32x4 acc[4][2];
    #pragma unroll
    for (int mi = 0; mi < 4; ++mi)
        #pragma unroll
        for (int ni = 0; ni < 2; ++ni)
            acc[mi][ni] = (f32x4)(0.0f);

    const size_t aBase0 = (size_t)((bm >> 4) + sA0) * kpan * 512;
    const size_t aBase1 = (size_t)((bm >> 4) + sA1) * kpan * 512;
    const size_t bBase  = (size_t)((bn >> 4) + wave) * kpan * 512;

    for (int k0 = 0; k0 < K; k0 += 32) {
        const size_t kp = (size_t)(k0 >> 5) * 512 + (size_t)lane * 8;
        gload16(G.ATh + aBase0 + kp, &Ah_[sA0 * 512]);
        gload16(G.ATh + aBase1 + kp, &Ah_[sA1 * 512]);
        if (full) {
            gload16(G.ATl + aBase0 + kp, &Al_[sA0 * 512]);
            gload16(G.ATl + aBase1 + kp, &Al_[sA1 * 512]);
        }
        gload16(G.BTh + bBase + kp, &Bh_[wave * 512]);
        if (wsplit)
            gload16(G.BTl + bBase + kp, &Bl_[wave * 512]);
        __syncthreads();
        bf16x8 a_h[4], a_l[4], b_h[2], b_l[2];
        #pragma unroll
        for (int mi = 0; mi < 4; ++mi) {
            const int s = (wave >> 1) * 4 + mi;
            a_h[mi] = *(const bf16x8*)&Ah_[s * 512 + g * 128 + rr * 8];
        }
        if (full) {
            #pragma unroll
            for (int mi = 0; mi < 4; ++mi) {
                const int s = (wave >> 1) * 4 + mi;
                a_l[mi] = *(const bf16x8*)&Al_[s * 512 + g * 128 + rr * 8];
            }
        }
        #pragma unroll
        for (int ni = 0; ni < 2; ++ni) {
            const int s = (wave & 1) * 2 + ni;
            b_h[ni] = *(const bf16x8*)&Bh_[s * 512 + g * 128 + rr * 8];
        }
        if (wsplit) {
            #pragma unroll
            for (int ni = 0; ni < 2; ++ni) {
                const int s = (wave & 1) * 2 + ni;
                b_l[ni] = *(const bf16x8*)&Bl_[s * 512 + g * 128 + rr * 8];
            }
        }
        #pragma unroll
        for (int mi = 0; mi < 4; ++mi)
            #pragma unroll
            for (int ni = 0; ni < 2; ++ni)
                acc[mi][ni] = __builtin_amdgcn_mfma_f32_16x16x32_bf16(a_h[mi], b_h[ni], acc[mi][ni], 0, 0, 0);
        if (wsplit) {
            #pragma unroll
            for (int mi = 0; mi < 4; ++mi)
                #pragma unroll
                for (int ni = 0; ni < 2; ++ni)
                    acc[mi][ni] = __builtin_amdgcn_mfma_f32_16x16x32_bf16(a_h[mi], b_l[ni], acc[mi][ni], 0, 0, 0);
        }
        if (full) {
            #pragma unroll
            for (int mi = 0; mi < 4; ++mi)
                #pragma unroll
                for (int ni = 0; ni < 2; ++ni)
                    acc[mi][ni] = __builtin_amdgcn_mfma_f32_16x16x32_bf16(a_l[mi], b_h[ni], acc[mi][ni], 0, 0, 0);
        }
        __syncthreads();
    }
    const int wm = (wave >> 1) * 64;
    const int wn = (wave & 1) * 32;
    const int epi = G.epi;
    #pragma unroll
    for (int mi = 0; mi < 4; ++mi)
        #pragma unroll
        for (int ni = 0; ni < 2; ++ni)
            #pragma unroll
            for (int q = 0; q < 4; ++q) {
                const int grow = bm + wm + mi * 16 + g * 4 + q;
                const int gcol = bn + wn + ni * 16 + rr;
                float x = acc[mi][ni][q];
                if (epi == 1) x = -0.6065306597126334f * sgm(x + G.bias[gcol]);
                else if (epi == 2) x = sgm(x + G.bias[gcol]);
                else if (epi == 3) {
                    const size_t o3 = (size_t)grow * G.N + gcol;
                    float vt = G.aux1[o3];
                    x = vt + sgm(x + G.bias[gcol]) * (G.aux2[o3] - vt);
                }
                else if (epi == 4) x = tanhf(x);
                else if (epi == 5) x = sgm(x);
                if (OSPLIT) {
                    if (gcol < G.kpanC * 32) {
                        unsigned short hh, ll;
                        split1(x, hh, ll);
                        const size_t off = toff1(grow, gcol, G.kpanC);
                        G.Ch[off] = hh; G.Cl[off] = ll;
                    }
                } else {
                    G.C[(size_t)grow * G.N + gcol] = x;
                }
            }
}

// ---------------- dedicated pure-bf16 GEMM, BK=64 (half the barrier drains) ----------
// Same MFMA accumulation order as mgemm nm=1 (panel 0 then panel 1) -> bit-identical.
// LDS = 24 KB (16K A + 8K B), same occupancy as mgemm; no epilogue switch.
__global__ __launch_bounds__(256, 2) void mgemm1(GBatch gb)
{
    __shared__ __align__(16) unsigned short Ah_[2 * 8 * 512];
    __shared__ __align__(16) unsigned short Bh_[2 * 4 * 512];
    const GSeg G = gb.s[blockIdx.z];
    const int bn = blockIdx.y * 64;
    if (bn >= G.N) return;
    const int K = G.K;
    const int kpan = K >> 5;
    const int lane = threadIdx.x & 63;
    const int wave = threadIdx.x >> 6;
    const int bm = blockIdx.x * 128;
    const int g = lane >> 4, rr = lane & 15;
    const int sA0 = wave, sA1 = wave + 4;

    f32x4 acc[4][2];
    #pragma unroll
    for (int mi = 0; mi < 4; ++mi)
        #pragma unroll
        for (int ni = 0; ni < 2; ++ni)
            acc[mi][ni] = (f32x4)(0.0f);

    const size_t aBase0 = (size_t)((bm >> 4) + sA0) * kpan * 512;
    const size_t aBase1 = (size_t)((bm >> 4) + sA1) * kpan * 512;
    const size_t bBase  = (size_t)((bn >> 4) + wave) * kpan * 512;

    for (int k0 = 0; k0 < K; k0 += 64) {
        const size_t kp0 = (size_t)(k0 >> 5) * 512 + (size_t)lane * 8;
        const size_t kp1 = kp0 + 512;
        gload16(G.ATh + aBase0 + kp0, &Ah_[sA0 * 512]);
        gload16(G.ATh + aBase1 + kp0, &Ah_[sA1 * 512]);
        gload16(G.ATh + aBase0 + kp1, &Ah_[4096 + sA0 * 512]);
        gload16(G.ATh + aBase1 + kp1, &Ah_[4096 + sA1 * 512]);
        gload16(G.BTh + bBase + kp0, &Bh_[wave * 512]);
        gload16(G.BTh + bBase + kp1, &Bh_[2048 + wave * 512]);
        __syncthreads();
        #pragma unroll
        for (int p = 0; p < 2; ++p) {
            bf16x8 a_h[4], b_h[2];
            #pragma unroll
            for (int mi = 0; mi < 4; ++mi) {
                const int s = (wave >> 1) * 4 + mi;
                a_h[mi] = *(const bf16x8*)&Ah_[p * 4096 + s * 512 + g * 128 + rr * 8];
            }
            #pragma unroll
            for (int ni = 0; ni < 2; ++ni) {
                const int s = (wave & 1) * 2 + ni;
                b_h[ni] = *(const bf16x8*)&Bh_[p * 2048 + s * 512 + g * 128 + rr * 8];
            }
            #pragma unroll
            for (int mi = 0; mi < 4; ++mi)
                #pragma unroll
                for (int ni = 0; ni < 2; ++ni)
                    acc[mi][ni] = __builtin_amdgcn_mfma_f32_16x16x32_bf16(a_h[mi], b_h[ni], acc[mi][ni], 0, 0, 0);
        }
        __syncthreads();
    }
    const int wm = (wave >> 1) * 64;
    const int wn = (wave & 1) * 32;
    #pragma unroll
    for (int mi = 0; mi < 4; ++mi)
        #pragma unroll
        for (int ni = 0; ni < 2; ++ni)
            #pragma unroll
            for (int q = 0; q < 4; ++q) {
                const int grow = bm + wm + mi * 16 + g * 4 + q;
                const int gcol = bn + wn + ni * 16 + rr;
                G.C[(size_t)grow * G.N + gcol] = acc[mi][ni][q];
            }
}

// kk = normalize_per_head(k * k_k); k <- k * (1 + (a-1)*k_a)   (in place)
__global__ __launch_bounds__(256) void prep_k(
    float* __restrict__ k, const float* __restrict__ a,
    const float* __restrict__ k_k, const float* __restrict__ k_a,
    float* __restrict__ kk)
{
    const int gid = blockIdx.x * 256 + threadIdx.x;
    const int j = gid & 63;
    const int h = (gid >> 6) & (NH_ - 1);
    const int ch = h * 64 + j;
    const float kv = k[gid];
    float kkv = kv * k_k[ch];
    float ss = kkv * kkv;
    #pragma unroll
    for (int m = 32; m; m >>= 1) ss += __shfl_xor(ss, m, 64);
    const float nrm = fmaxf(sqrtf(ss), 1e-12f);
    kk[gid] = kkv / nrm;
    const float av = a[gid];
    k[gid] = kv * (1.0f + (av - 1.0f) * k_a[ch]);
}

// ---------------- Chunked RWKV7 scan (NC=64, CL=32) ----------------
// Phase A: 4-wave blocks; waves 0,1 = Q halves (cols 0-31 / 32-63);
// waves 2,3 = U halves. LDS stage + cross-wave partials.
__global__ __launch_bounds__(256, 1) void chunk_AU(
    const float* __restrict__ w, const float* __restrict__ k,
    const float* __restrict__ v, const float* __restrict__ kk,
    const float* __restrict__ a,
    float* __restrict__ Pbuf, float* __restrict__ Ubuf)
{
    const int bid = blockIdx.x;
    const int c = bid & (NC - 1);
    const int bh = bid >> 6;
    const int b = bh >> 4, h = bh & (NH_ - 1);
    const int tid = threadIdx.x;
    const int wv_ = tid >> 6;
    const int half = wv_ & 1;
    const bool isU = wv_ >= 2;
    const int lane = tid & 63;
    __shared__ __align__(16) float ew_s[64], ah_s[64], bh_s[64], kh_s[64], vh_s[64];
    __shared__ float part[4][64];

#define DECL_X(i) f4 x##i = f4splat(0.0f);
    REP8(DECL_X)
#undef DECL_X
    if (!isU) {
        const int local = lane - half * 32;
#define INIT_Q(i) \
        if (local == 4*i+0) x##i.x = 1.0f; \
        else if (local == 4*i+1) x##i.y = 1.0f; \
        else if (local == 4*i+2) x##i.z = 1.0f; \
        else if (local == 4*i+3) x##i.w = 1.0f;
        REP8(INIT_Q)
#undef INIT_Q
    }

    size_t idx = (((size_t)b * T_ + (size_t)c * CL) * NH_ + h) * 64 + lane;
    float wvv = 0, kkv = 0, av = 0, kv = 0, vvv = 0;
    if (wv_ == 0) { wvv = w[idx]; kkv = kk[idx]; av = a[idx]; }
    else if (wv_ == 1) { kv = k[idx]; vvv = v[idx]; }

    for (int t = 0; t < CL; ++t) {
        if (wv_ == 0) {
            ew_s[lane] = expf(wvv);
            ah_s[lane] = -kkv;
            bh_s[lane] = kkv * av;
        } else if (wv_ == 1) {
            kh_s[lane] = kv;
            vh_s[lane] = vvv;
        }
        __syncthreads();                                   // b1: stage ready
        if (t + 1 < CL) {
            idx += NH_ * 64;
            if (wv_ == 0) { wvv = w[idx]; kkv = kk[idx]; av = a[idx]; }
            else if (wv_ == 1) { kv = k[idx]; vvv = v[idx]; }
        }
        const f4* A4 = (const f4*)ah_s + half * 8;
        f4 da = f4splat(0.0f);
#define DOT_(i) { da += x##i * A4[i]; }
        REP8(DOT_)
#undef DOT_
        part[wv_][lane] = hsum4(da);
        __syncthreads();                                   // b2: partials ready
        const float D = isU ? part[2][lane] + part[3][lane]
                            : part[0][lane] + part[1][lane];
        const float vcur = vh_s[lane];
        const f4* E4 = (const f4*)ew_s + half * 8;
        const f4* B4 = (const f4*)bh_s + half * 8;
        const f4* K4 = (const f4*)kh_s + half * 8;
        if (!isU) {
#define UPDQ_(i) { x##i = x##i * E4[i] + D * B4[i]; }
            REP8(UPDQ_)
#undef UPDQ_
        } else {
#define UPDU_(i) { x##i = x##i * E4[i] + D * B4[i] + vcur * K4[i]; }
            REP8(UPDU_)
#undef UPDU_
        }
        __syncthreads();                                   // b3: end of step
    }
    float* Dst = (isU ? Ubuf : Pbuf)
               + (((size_t)bh * NC + c) * 64 + lane) * 64 + half * 32;
#define ST_(i) ((f4*)Dst)[i] = x##i;
    REP8(ST_)
#undef ST_
}

// Phase B: barrier-free register-resident chunk scan.
__global__ __launch_bounds__(64) void chunk_scan(
    const float* __restrict__ Pbuf, float* __restrict__ USbuf)
{
    const int wg = (blockIdx.x & 7) * 64 + (blockIdx.x >> 3);
    const int bh = wg >> 4;
    const int rg = wg & 15;
    const int j = threadIdx.x;
    const int r0 = rg * 4;

    float a0 = 0, a1 = 0, a2 = 0, a3 = 0;
    float u0, u1, u2, u3;
    float pA[64], pB[64];

    const size_t base = (size_t)bh * NC * 4096;
    {
        const float* Pb = Pbuf + base + j;
        #pragma unroll
        for (int k2 = 0; k2 < 64; ++k2) pA[k2] = Pb[k2 * 64];
        const float* Ub = USbuf + base + r0 * 64 + j;
        u0 = Ub[0]; u1 = Ub[64]; u2 = Ub[128]; u3 = Ub[192];
    }

#define SCAN_STEP(PC, PN, c) { \
    float n0 = u0, n1 = u1, n2 = u2, n3 = u3; \
    float* Ub = USbuf + base + (size_t)(c) * 4096 + r0 * 64 + j; \
    Ub[0] = a0; Ub[64] = a1; Ub[128] = a2; Ub[192] = a3; \
    if ((c) + 1 < NC) { \
        const float* Un = USbuf + base + (size_t)((c) + 1) * 4096 + r0 * 64 + j; \
        u0 = Un[0]; u1 = Un[64]; u2 = Un[128]; u3 = Un[192]; \
        const float* Pn = Pbuf + base + (size_t)((c) + 1) * 4096 + j; \
        _Pragma("unroll") \
        for (int k2 = 0; k2 < 64; ++k2) PN[k2] = Pn[k2 * 64]; \
    } \
    _Pragma("unroll") \
    for (int k2 = 0; k2 < 64; ++k2) { \
        const float s0 = rdlane(a0, k2), s1 = rdlane(a1, k2); \
        const float s2 = rdlane(a2, k2), s3 = rdlane(a3, k2); \
        n0 += s0 * PC[k2]; n1 += s1 * PC[k2]; \
        n2 += s2 * PC[k2]; n3 += s3 * PC[k2]; \
    } \
    a0 = n0; a1 = n1; a2 = n2; a3 = n3; }

    for (int c = 0; c < NC; c += 2) {
        SCAN_STEP(pA, pB, c)
        SCAN_STEP(pB, pA, c + 1)
    }
#undef SCAN_STEP
}

// Phase C + fused GroupNorm/readout/gate: one wave per (bh,c); S register-resident
// (lane = value-dim row). og written as bf16-hi only (out-projection is nm=1).
__global__ __launch_bounds__(256) void chunk_out_fused(
    const float* __restrict__ r, const float* __restrict__ w,
    const float* __restrict__ k, const float* __restrict__ v,
    const float* __restrict__ kk, const float* __restrict__ a,
    const float* __restrict__ Scbuf, const float* __restrict__ g,
    const float* __restrict__ r_k, const float* __restrict__ gn_w,
    const float* __restrict__ gn_b,
    unsigned short* __restrict__ og_h)
{
    const int gw = blockIdx.x * 4 + (threadIdx.x >> 6);   // 0..2047
    const int c = gw & (NC - 1);
    const int bh = gw >> 6;
    const int b = bh >> 4, h = bh & (NH_ - 1);
    const int lane = threadIdx.x & 63;
    const int ch = h * 64 + lane;
    const float rk_c = r_k[ch];
    const float gnw_c = gn_w[ch];
    const float gnb_c = gn_b[ch];

    float s[64];
    {
        const float* Srow = Scbuf + (((size_t)bh * NC + c) * 64 + lane) * 64;
        #pragma unroll
        for (int j = 0; j < 64; ++j) s[j] = Srow[j];
    }

    size_t idx = (((size_t)b * T_ + (size_t)c * CL) * NH_ + h) * 64 + lane;
    int rowTok = b * T_ + c * CL;
    float wv = w[idx], kkv = kk[idx], av = a[idx], kv = k[idx], rv = r[idx],
          vv = v[idx], gv = g[idx];

    for (int t = 0; t < CL; ++t) {
        const float e_own = expf(wv);
        const float ah_own = -kkv;
        const float bh_own = kkv * av;
        const float k_own = kv;
        const float r_own = rv;
        const float v_own = vv;
        const float g_own = gv;
        if (t + 1 < CL) {
            idx += NH_ * 64;
            wv = w[idx]; kkv = kk[idx]; av = a[idx]; kv = k[idx]; rv = r[idx];
            vv = v[idx]; gv = g[idx];
        }
        float d0 = 0, d1 = 0, d2 = 0, d3 = 0;
        #pragma unroll
        for (int j = 0; j < 64; j += 4) {
            d0 += s[j]     * rdlane(ah_own, j);
            d1 += s[j + 1] * rdlane(ah_own, j + 1);
            d2 += s[j + 2] * rdlane(ah_own, j + 2);
            d3 += s[j + 3] * rdlane(ah_own, j + 3);
        }
        const float sa = (d0 + d1) + (d2 + d3);
        float o0 = 0, o1 = 0, o2 = 0, o3 = 0;
        #pragma unroll
        for (int j = 0; j < 64; j += 4) {
            {
                const float ej = rdlane(e_own, j), bj = rdlane(bh_own, j);
                const float kj = rdlane(k_own, j), rj = rdlane(r_own, j);
                s[j] = s[j] * ej + sa * bj + v_own * kj; o0 += s[j] * rj;
            }
            {
                const float ej = rdlane(e_own, j + 1), bj = rdlane(bh_own, j + 1);
                const float kj = rdlane(k_own, j + 1), rj = rdlane(r_own, j + 1);
                s[j + 1] = s[j + 1] * ej + sa * bj + v_own * kj; o1 += s[j + 1] * rj;
            }
            {
                const float ej = rdlane(e_own, j + 2), bj = rdlane(bh_own, j + 2);
                const float kj = rdlane(k_own, j + 2), rj = rdlane(r_own, j + 2);
                s[j + 2] = s[j + 2] * ej + sa * bj + v_own * kj; o2 += s[j + 2] * rj;
            }
            {
                const float ej = rdlane(e_own, j + 3), bj = rdlane(bh_own, j + 3);
                const float kj = rdlane(k_own, j + 3), rj = rdlane(r_own, j + 3);
                s[j + 3] = s[j + 3] * ej + sa * bj + v_own * kj; o3 += s[j + 3] * rj;
            }
        }
        const float ov = (o0 + o1) + (o2 + o3);
        // fused GroupNorm(64) + r_k readout + output gate
        float s1r = ov, s2r = ov * ov, term = r_own * k_own * rk_c;
        #pragma unroll
        for (int m = 32; m; m >>= 1) {
            s1r += __shfl_xor(s1r, m, 64);
            s2r += __shfl_xor(s2r, m, 64);
            term += __shfl_xor(term, m, 64);
        }
        const float mu = s1r * (1.0f / 64.0f);
        const float var = s2r * (1.0f / 64.0f) - mu * mu;
        const float on = (ov - mu) * rsqrtf(var + 6.4e-4f);
        const float outv = (on * gnw_c + gnb_c + term * v_own) * g_own;
        og_h[toff1(rowTok, ch, 32)] =
            (unsigned short)(__float_as_uint(outv) >> 16);
        ++rowTok;
    }
}

extern "C" void kernel_launch(void* const* d_in, const int* in_sizes, int n_in,
                              void* d_out, int out_size, void* d_ws, size_t ws_size,
                              hipStream_t stream)
{
    const float* hs      = (const float*)d_in[0];
    const float* context = (const float*)d_in[1];
    const float* v_first = (const float*)d_in[2];
    const float* x_r = (const float*)d_in[3];
    const float* x_w = (const float*)d_in[4];
    const float* x_k = (const float*)d_in[5];
    const float* x_v = (const float*)d_in[6];
    const float* x_a = (const float*)d_in[7];
    const float* x_g = (const float*)d_in[8];
    const float* k_k = (const float*)d_in[9];
    const float* k_a = (const float*)d_in[10];
    const float* r_k = (const float*)d_in[11];
    const float* W_r = (const float*)d_in[12];
    const float* W_k = (const float*)d_in[13];
    const float* W_v = (const float*)d_in[14];
    const float* W_o = (const float*)d_in[15];
    const float* W_cond = (const float*)d_in[16];
    const float* wA = (const float*)d_in[17];
    const float* wB = (const float*)d_in[18];
    const float* wb = (const float*)d_in[19];
    const float* aA = (const float*)d_in[20];
    const float* aB = (const float*)d_in[21];
    const float* ab = (const float*)d_in[22];
    const float* gA = (const float*)d_in[23];
    const float* gB = (const float*)d_in[24];
    const float* vA = (const float*)d_in[25];
    const float* vB = (const float*)d_in[26];
    const float* vb = (const float*)d_in[27];
    const float* gn_w = (const float*)d_in[28];
    const float* gn_b = (const float*)d_in[29];
    (void)in_sizes; (void)n_in; (void)out_size; (void)ws_size;

    float* ws = (float*)d_ws;
    float* cp    = ws;                   // [1024,1024] f32
    float* rbuf  = cp    + (1 << 20);
    float* kbuf  = rbuf  + (4 << 20);
    float* vtmp  = kbuf  + (4 << 20);    // raw v
    float* wbuf  = vtmp  + (4 << 20);    // log-decay w
    float* abuf  = wbuf  + (4 << 20);
    float* obuf  = abuf  + (4 << 20);    // alias xr hi; later og hi
    float* kkbuf = obuf  + (4 << 20);    // alias xg hi
    float* gbuf  = kkbuf + (4 << 20);    // alias xk hi
    float* vbuf  = gbuf  + (4 << 20);    // alias xv hi
    float* Pbuf  = vbuf  + (4 << 20);    // 8M; xw pair aliases
    float* Ubuf  = Pbuf  + (8 << 20);    // 8M: U then in-place chunk-start states; xa hi aliases
    float* endf  = Ubuf  + (8 << 20);

    unsigned short* xr_h = (unsigned short*)obuf;
    unsigned short* xw_h = (unsigned short*)Pbuf;  unsigned short* xw_l = xw_h + (4 << 20);
    unsigned short* xa_h = (unsigned short*)Ubuf;
    unsigned short* xg_h = (unsigned short*)kkbuf;
    unsigned short* xk_h = (unsigned short*)gbuf;
    unsigned short* xv_h = (unsigned short*)vbuf;
    // og hi lives in the obuf region (xr hi dead after r-projection)
    unsigned short* og_h = (unsigned short*)obuf;

    unsigned short* u = (unsigned short*)endf;
    unsigned short* ctx_h = u;  u += 786432;
    unsigned short* w1h = u;    u += 262144;
    unsigned short* w1l = u;    u += 262144;
    unsigned short* a1h = u;    u += 262144;
    unsigned short* a1l = u;    u += 262144;
    unsigned short* g1h = u;    u += 524288;
    unsigned short* g1l = u;    u += 524288;
    unsigned short* v1h = u;    u += 131072;
    unsigned short* v1l = u;    u += 131072;
    unsigned short* condT_h = u; u += 786432;
    unsigned short* condT_l = u; u += 786432;
    unsigned short* rT_h = u;    u += 1048576;
    unsigned short* rT_l = u;    u += 1048576;
    unsigned short* kT_h = u;    u += 1048576;
    unsigned short* kT_l = u;    u += 1048576;
    unsigned short* vT_h = u;    u += 1048576;
    unsigned short* vT_l = u;    u += 1048576;
    unsigned short* oT_h = u;    u += 1048576;
    unsigned short* oT_l = u;    u += 1048576;
    unsigned short* waT_h = u;   u += 65536;
    unsigned short* waT_l = u;   u += 65536;
    unsigned short* wbT_h = u;   u += 65536;
    unsigned short* wbT_l = u;   u += 65536;
    unsigned short* aaT_h = u;   u += 65536;
    unsigned short* aaT_l = u;   u += 65536;
    unsigned short* abT_h = u;   u += 65536;
    unsigned short* abT_l = u;   u += 65536;
    unsigned short* gaT_h = u;   u += 131072;
    unsigned short* gaT_l = u;   u += 131072;
    unsigned short* gbT_h = u;   u += 131072;
    unsigned short* gbT_l = u;   u += 131072;
    unsigned short* vaT_h = u;   u += 65536;   // N padded 16->64
    unsigned short* vaT_l = u;   u += 65536;
    unsigned short* vbT_h = u;   u += 32768;   // K padded 16->32
    unsigned short* vbT_l = u;   u += 32768;

    const dim3 blk(256);
    // ---- fused weight transposes + RNE split -> panel-tiled (padded) ----
    {
        WAll all;
        auto seg = [](const float* W, unsigned short* Th, unsigned short* Tl,
                      int K, int N, int Kpad, int Npad, int tile0) {
            WSeg s; s.W = W; s.Th = Th; s.Tl = Tl; s.K = K; s.N = N;
            s.kpan = Kpad / 32; s.tile0 = tile0; s.tilesN = Npad / 32; return s;
        };
        int t0 = 0;
        all.s[0]  = seg(W_cond, condT_h, condT_l, 768, 1024, 768, 1024, t0);  t0 += 24 * 32;
        all.s[1]  = seg(W_r, rT_h, rT_l, 1024, 1024, 1024, 1024, t0);         t0 += 32 * 32;
        all.s[2]  = seg(W_k, kT_h, kT_l, 1024, 1024, 1024, 1024, t0);         t0 += 32 * 32;
        all.s[3]  = seg(W_v, vT_h, vT_l, 1024, 1024, 1024, 1024, t0);         t0 += 32 * 32;
        all.s[4]  = seg(W_o, oT_h, oT_l, 1024, 1024, 1024, 1024, t0);         t0 += 32 * 32;
        all.s[5]  = seg(wA, waT_h, waT_l, 1024, 64, 1024, 64, t0);            t0 += 32 * 2;
        all.s[6]  = seg(wB, wbT_h, wbT_l, 64, 1024, 64, 1024, t0);            t0 += 2 * 32;
        all.s[7]  = seg(aA, aaT_h, aaT_l, 1024, 64, 1024, 64, t0);            t0 += 32 * 2;
        all.s[8]  = seg(aB, abT_h, abT_l, 64, 1024, 64, 1024, t0);            t0 += 2 * 32;
        all.s[9]  = seg(gA, gaT_h, gaT_l, 1024, 128, 1024, 128, t0);          t0 += 32 * 4;
        all.s[10] = seg(gB, gbT_h, gbT_l, 128, 1024, 128, 1024, t0);          t0 += 4 * 32;
        all.s[11] = seg(vA, vaT_h, vaT_l, 1024, 16, 1024, 64, t0);            t0 += 32 * 2;
        all.s[12] = seg(vB, vbT_h, vbT_l, 16, 1024, 32, 1024, t0);            t0 += 1 * 32;
        wtrans_all<<<dim3(t0), blk, 0, stream>>>(all);
    }

    auto GS = [](const unsigned short* ah, const unsigned short* al,
                 const unsigned short* bh, const unsigned short* bl,
                 float* c, unsigned short* ch, unsigned short* cl,
                 int K, int N, int kpanC, int epi, int nm,
                 const float* bias, const float* a1, const float* a2) {
        GSeg s; s.ATh = ah; s.ATl = al; s.BTh = bh; s.BTl = bl;
        s.C = c; s.Ch = ch; s.Cl = cl; s.bias = bias; s.aux1 = a1; s.aux2 = a2;
        s.K = K; s.N = N; s.kpanC = kpanC; s.epi = epi; s.nm = nm; return s;
    };

    // ---- activations (panel-tiled pre-split) ----
    ctx_split<<<dim3(768), blk, 0, stream>>>(context, ctx_h);
    hs_lerp4<<<dim3(4096), blk, 0, stream>>>(hs, x_r, x_w, x_a, x_g,
                                             xr_h, xw_h, xw_l, xa_h, xg_h);
    {
        GBatch gb;
        gb.s[0] = GS(ctx_h, nullptr, condT_h, nullptr, cp, nullptr, nullptr,
                     768, 1024, 0, 0, 1, nullptr, nullptr, nullptr);
        gb.s[1] = gb.s[0]; gb.s[2] = gb.s[0]; gb.s[3] = gb.s[0];
        mgemm1<<<dim3(8, 16, 1), blk, 0, stream>>>(gb);
    }
    ctx_lerp2<<<dim3(4096), blk, 0, stream>>>(cp, x_k, x_v, xk_h, xv_h);

    // ---- main projections r/k/v batched over grid.z (pure bf16, BK=64) ----
    {
        GBatch gb;
        gb.s[0] = GS(xr_h, nullptr, rT_h, nullptr, rbuf, nullptr, nullptr,
                     1024, 1024, 0, 0, 1, nullptr, nullptr, nullptr);
        gb.s[1] = GS(xk_h, nullptr, kT_h, nullptr, kbuf, nullptr, nullptr,
                     1024, 1024, 0, 0, 1, nullptr, nullptr, nullptr);
        gb.s[2] = GS(xv_h, nullptr, vT_h, nullptr, vtmp, nullptr, nullptr,
                     1024, 1024, 0, 0, 1, nullptr, nullptr, nullptr);
        gb.s[3] = gb.s[0];
        mgemm1<<<dim3(32, 16, 3), blk, 0, stream>>>(gb);
    }
    // ---- LoRA stage 1: 4 GEMMs in one z-batched launch (panel-tiled outputs).
    // w stays nm=3 (decay exp-compounds); a/g/v sigmoid-damped -> nm=1. ----
    {
        GBatch gb;
        gb.s[0] = GS(xw_h, xw_l, waT_h, waT_l, nullptr, w1h, w1l,
                     1024, 64, 2, 4, 3, nullptr, nullptr, nullptr);
        gb.s[1] = GS(xa_h, nullptr, aaT_h, nullptr, nullptr, a1h, a1l,
                     1024, 64, 2, 0, 1, nullptr, nullptr, nullptr);
        gb.s[2] = GS(xg_h, nullptr, gaT_h, nullptr, nullptr, g1h, g1l,
                     1024, 128, 4, 5, 1, nullptr, nullptr, nullptr);
        gb.s[3] = GS(xv_h, nullptr, vaT_h, nullptr, nullptr, v1h, v1l,
                     1024, 64, 1, 0, 1, nullptr, nullptr, nullptr);
        mgemm<1><<<dim3(32, 2, 4), blk, 0, stream>>>(gb, 4096);
    }
    // ---- LoRA stage 2: 4 GEMMs in one z-batched launch (all nm=3: tiny K) ----
    {
        GBatch gb;
        gb.s[0] = GS(w1h, w1l, wbT_h, wbT_l, wbuf, nullptr, nullptr,
                     64, 1024, 0, 1, 3, wb, nullptr, nullptr);
        gb.s[1] = GS(a1h, a1l, abT_h, abT_l, abuf, nullptr, nullptr,
                     64, 1024, 0, 2, 3, ab, nullptr, nullptr);
        gb.s[2] = GS(g1h, g1l, gbT_h, gbT_l, gbuf, nullptr, nullptr,
                     128, 1024, 0, 0, 3, nullptr, nullptr, nullptr);
        gb.s[3] = GS(v1h, v1l, vbT_h, vbT_l, vbuf, nullptr, nullptr,
                     32, 1024, 0, 3, 3, vb, vtmp, v_first);
        mgemm<0><<<dim3(32, 16, 4), blk, 0, stream>>>(gb, 4096);
    }

    // ---- recurrence ----
    prep_k<<<dim3(16384), blk, 0, stream>>>(kbuf, abuf, k_k, k_a, kkbuf);
    chunk_AU<<<dim3(2048), dim3(256), 0, stream>>>(wbuf, kbuf, vbuf, kkbuf, abuf, Pbuf, Ubuf);
    chunk_scan<<<dim3(512), dim3(64), 0, stream>>>(Pbuf, Ubuf);
    chunk_out_fused<<<dim3(512), dim3(256), 0, stream>>>(rbuf, wbuf, kbuf, vbuf, kkbuf, abuf,
                                                         Ubuf, gbuf, r_k, gn_w, gn_b, og_h);

    // ---- output projection (pure bf16, BK=64) ----
    {
        GBatch gb;
        gb.s[0] = GS(og_h, nullptr, oT_h, nullptr, (float*)d_out, nullptr, nullptr,
                     1024, 1024, 0, 0, 1, nullptr, nullptr, nullptr);
        gb.s[1] = gb.s[0]; gb.s[2] = gb.s[0]; gb.s[3] = gb.s[0];
        mgemm1<<<dim3(32, 16, 1), blk, 0, stream>>>(gb);
    }
}